// Round 2
// baseline (208.997 us; speedup 1.0000x reference)
//
#include <hip/hip_runtime.h>
#include <hip/hip_bf16.h>

#define Bdim 4096
#define Ldim 4096
#define Hdim 1024
#define TILE 128
#define BK 64

typedef __attribute__((ext_vector_type(8))) __bf16 bf16x8;
typedef __attribute__((ext_vector_type(4))) float floatx4;

__device__ __forceinline__ unsigned short f2bf(float f) {
  union { __hip_bfloat16 h; unsigned short u; } c;
  c.h = __float2bfloat16(f);
  return c.u;
}

// ---- fused prep: blocks [0,Ldim) do W->bf16 + bias row; [Ldim, Ldim+Bdim) do X->bf16 row
__global__ __launch_bounds__(256) void prep_kernel(
    const float* __restrict__ X, const float* __restrict__ E,
    const float* __restrict__ W, const float* __restrict__ b,
    unsigned short* __restrict__ Xb, unsigned short* __restrict__ Wb,
    float* __restrict__ bias) {
  const int blk = blockIdx.x;
  const int t = threadIdx.x;
  if (blk < Ldim) {
    const int row = blk;
    const float4 wv = reinterpret_cast<const float4*>(W + (size_t)row * Hdim)[t];
    const float4 ev = reinterpret_cast<const float4*>(E + (size_t)row * Hdim)[t];
    ushort4 o;
    o.x = f2bf(wv.x); o.y = f2bf(wv.y); o.z = f2bf(wv.z); o.w = f2bf(wv.w);
    reinterpret_cast<ushort4*>(Wb + (size_t)row * Hdim)[t] = o;
    float dot = wv.x * ev.x + wv.y * ev.y + wv.z * ev.z + wv.w * ev.w;
#pragma unroll
    for (int off = 32; off > 0; off >>= 1) dot += __shfl_down(dot, off, 64);
    __shared__ float part[4];
    if ((t & 63) == 0) part[t >> 6] = dot;
    __syncthreads();
    if (t == 0) bias[row] = part[0] + part[1] + part[2] + part[3] + b[row];
  } else {
    const int i = (blk - Ldim) * 256 + t;   // float4 index into X
    float4 v = reinterpret_cast<const float4*>(X)[i];
    ushort4 o;
    o.x = f2bf(v.x); o.y = f2bf(v.y); o.z = f2bf(v.z); o.w = f2bf(v.w);
    reinterpret_cast<ushort4*>(Xb)[i] = o;
  }
}

// ---- C[B,L] = Xb @ Wb^T + bias -----------------------------------------
// 128x128 tile, BK=64, 4 waves, each wave 64x64 via 4x4 MFMA 16x16x32 tiles.
// LDS layout: per 16-row block (1024 shorts = 2 KB), chunk(16B) index =
// kchunk*16 + row  (k-major). Fragment reads are then base + lane*16B:
// lane-linear => zero bank conflicts. Staging permutes global addresses to
// match (global_load_lds dest is always wave-base + lane*16B).
__global__ __launch_bounds__(256) void gemm_bias_kernel(
    const unsigned short* __restrict__ A,   // [Bdim][Hdim] bf16 bits
    const unsigned short* __restrict__ Bw,  // [Ldim][Hdim] bf16 bits
    const float* __restrict__ bias,         // [Ldim]
    float* __restrict__ C) {                // [Bdim][Ldim] fp32
  __shared__ __align__(16) unsigned short lA[TILE * BK];   // 16 KB
  __shared__ __align__(16) unsigned short lB[TILE * BK];   // 16 KB

  const int tid = threadIdx.x;
  const int wave = tid >> 6;
  const int lane = tid & 63;
  const int m_blk = blockIdx.y * TILE;
  const int n_blk = blockIdx.x * TILE;

  const int lrow = lane & 15;   // row within 16-row block
  const int lkc = lane >> 4;    // k-chunk quad 0..3

  // staging: wave stages rows [wave*32, wave*32+32) = two 16-row blocks.
  // lane loads global (row = base + lrow, kchunk = j*4 + lkc) -> LDS chunk lane.
  const unsigned short* gA =
      A + (size_t)(m_blk + wave * 32 + lrow) * Hdim + lkc * 8;
  const unsigned short* gB =
      Bw + (size_t)(n_blk + wave * 32 + lrow) * Hdim + lkc * 8;
  unsigned short* lA0 = lA + wave * 2048;   // wave's two 16-row blocks
  unsigned short* lB0 = lB + wave * 2048;

  // compute sub-tile origin for this wave
  const int wm = (wave >> 1) * 64;
  const int wn = (wave & 1) * 64;
  const unsigned short* pa = lA + (wm >> 4) * 1024 + lane * 8;  // + mi*1024 + kk*512
  const unsigned short* pb = lB + (wn >> 4) * 1024 + lane * 8;

  floatx4 acc[4][4] = {};

  for (int kt = 0; kt < Hdim / BK; ++kt) {
    __syncthreads();  // previous iter done reading LDS
#define GLL(src, dst)                                                  \
    __builtin_amdgcn_global_load_lds(                                  \
        (const __attribute__((address_space(1))) void*)(src),          \
        (__attribute__((address_space(3))) void*)(dst), 16, 0, 0)
    GLL(gA, lA0);                                  // b16=0, j=0
    GLL(gA + 32, lA0 + 512);                       // b16=0, j=1
    GLL(gA + 16 * Hdim, lA0 + 1024);               // b16=1, j=0
    GLL(gA + 16 * Hdim + 32, lA0 + 1536);          // b16=1, j=1
    GLL(gB, lB0);
    GLL(gB + 32, lB0 + 512);
    GLL(gB + 16 * Hdim, lB0 + 1024);
    GLL(gB + 16 * Hdim + 32, lB0 + 1536);
#undef GLL
    gA += BK;
    gB += BK;
    __syncthreads();  // staging visible

#pragma unroll
    for (int kk = 0; kk < 2; ++kk) {
      bf16x8 af[4], bfr[4];
#pragma unroll
      for (int i = 0; i < 4; ++i) {
        af[i]  = *reinterpret_cast<const bf16x8*>(pa + i * 1024 + kk * 512);
        bfr[i] = *reinterpret_cast<const bf16x8*>(pb + i * 1024 + kk * 512);
      }
#pragma unroll
      for (int mi = 0; mi < 4; ++mi)
#pragma unroll
        for (int ni = 0; ni < 4; ++ni)
          acc[mi][ni] = __builtin_amdgcn_mfma_f32_16x16x32_bf16(
              af[mi], bfr[ni], acc[mi][ni], 0, 0, 0);
    }
  }

  // epilogue: C/D layout col=lane&15, row=(lane>>4)*4+reg  [m89-verified]
  const int col0 = n_blk + wn + lrow;
  const int row0 = m_blk + wm + lkc * 4;
#pragma unroll
  for (int ni = 0; ni < 4; ++ni) {
    const float bs = bias[col0 + ni * 16];
#pragma unroll
    for (int mi = 0; mi < 4; ++mi) {
      float* cp = C + (size_t)(row0 + mi * 16) * Ldim + (col0 + ni * 16);
      floatx4 v = acc[mi][ni];
      cp[0 * (size_t)Ldim] = v.x + bs;
      cp[1 * (size_t)Ldim] = v.y + bs;
      cp[2 * (size_t)Ldim] = v.z + bs;
      cp[3 * (size_t)Ldim] = v.w + bs;
    }
  }
}

extern "C" void kernel_launch(void* const* d_in, const int* in_sizes, int n_in,
                              void* d_out, int out_size, void* d_ws, size_t ws_size,
                              hipStream_t stream) {
  const float* X = (const float*)d_in[0];  // bert_output [B,H]
  const float* E = (const float*)d_in[1];  // label_embed [L,H]
  const float* W = (const float*)d_in[2];  // W [L,H]
  const float* b = (const float*)d_in[3];  // b [L]
  // d_in[4] = labels, unused by the reference output.
  float* out = (float*)d_out;

  unsigned short* Xb = (unsigned short*)d_ws;                 // 8 MB
  unsigned short* Wb = Xb + (size_t)Bdim * Hdim;              // 8 MB
  float* bias = (float*)(Wb + (size_t)Ldim * Hdim);           // 16 KB

  prep_kernel<<<Ldim + Bdim, 256, 0, stream>>>(X, E, W, b, Xb, Wb, bias);
  dim3 grid(Ldim / TILE, Bdim / TILE);
  gemm_bias_kernel<<<grid, 256, 0, stream>>>(Xb, Wb, bias, out);
}

// Round 3
// 192.359 us; speedup vs baseline: 1.0865x; 1.0865x over previous
//
#include <hip/hip_runtime.h>
#include <hip/hip_bf16.h>

#define Bdim 4096
#define Ldim 4096
#define Hdim 1024
#define TILE 128
#define BK 32

typedef __attribute__((ext_vector_type(8))) __bf16 bf16x8;
typedef __attribute__((ext_vector_type(4))) float floatx4;

__device__ __forceinline__ unsigned short f2bf(float f) {
  union { __hip_bfloat16 h; unsigned short u; } c;
  c.h = __float2bfloat16(f);
  return c.u;
}

// ---- fused prep: blocks [0,Ldim) do W->bf16 + bias row; [Ldim, Ldim+Bdim) do X->bf16 row
__global__ __launch_bounds__(256) void prep_kernel(
    const float* __restrict__ X, const float* __restrict__ E,
    const float* __restrict__ W, const float* __restrict__ b,
    unsigned short* __restrict__ Xb, unsigned short* __restrict__ Wb,
    float* __restrict__ bias) {
  const int blk = blockIdx.x;
  const int t = threadIdx.x;
  if (blk < Ldim) {
    const int row = blk;
    const float4 wv = reinterpret_cast<const float4*>(W + (size_t)row * Hdim)[t];
    const float4 ev = reinterpret_cast<const float4*>(E + (size_t)row * Hdim)[t];
    ushort4 o;
    o.x = f2bf(wv.x); o.y = f2bf(wv.y); o.z = f2bf(wv.z); o.w = f2bf(wv.w);
    reinterpret_cast<ushort4*>(Wb + (size_t)row * Hdim)[t] = o;
    float dot = wv.x * ev.x + wv.y * ev.y + wv.z * ev.z + wv.w * ev.w;
#pragma unroll
    for (int off = 32; off > 0; off >>= 1) dot += __shfl_down(dot, off, 64);
    __shared__ float part[4];
    if ((t & 63) == 0) part[t >> 6] = dot;
    __syncthreads();
    if (t == 0) bias[row] = part[0] + part[1] + part[2] + part[3] + b[row];
  } else {
    const int i = (blk - Ldim) * 256 + t;   // float4 index into X
    float4 v = reinterpret_cast<const float4*>(X)[i];
    ushort4 o;
    o.x = f2bf(v.x); o.y = f2bf(v.y); o.z = f2bf(v.z); o.w = f2bf(v.w);
    reinterpret_cast<ushort4*>(Xb)[i] = o;
  }
}

// ---- C[B,L] = Xb @ Wb^T + bias -----------------------------------------
// 128x128 tile, BK=32, 4 waves, each wave 64x64 via 4x4 MFMA 16x16x32 tiles.
//
// LDS layout per 16-row block (64 chunks of 16B = 1 KB): chunk c holds
// (row = c>>2, kchunk = (c&3) ^ ((c>>2)&3))  — XOR swizzle.
//  * GLL staging: lane L writes chunk L (HW-fixed); its global address is
//    row = L>>2, kchunk = (L&3)^((L>>2)&3): each 4-lane quad covers one
//    contiguous 64B row-segment (permuted inside one cacheline) -> coalesced.
//  * Fragment read: lane (lrow, lkc) reads chunk lrow*4 + (lkc^(lrow&3)):
//    bank-groups are uniformly covered (8 lanes per 4-bank group) -> no
//    8-way pile-up (R1 had 4.19M conflict cycles from the unswizzled form).
__global__ __launch_bounds__(256) void gemm_bias_kernel(
    const unsigned short* __restrict__ A,   // [Bdim][Hdim] bf16 bits
    const unsigned short* __restrict__ Bw,  // [Ldim][Hdim] bf16 bits
    const float* __restrict__ bias,         // [Ldim]
    float* __restrict__ C) {                // [Bdim][Ldim] fp32
  __shared__ __align__(16) unsigned short lA[TILE * BK];   // 8 KB
  __shared__ __align__(16) unsigned short lB[TILE * BK];   // 8 KB

  const int tid = threadIdx.x;
  const int wave = tid >> 6;
  const int lane = tid & 63;
  const int m_blk = blockIdx.y * TILE;
  const int n_blk = blockIdx.x * TILE;

  // staging addresses (XOR-swizzled within each 64B quad)
  const int sr = lane >> 2;                      // row within 16-row block
  const int sq = (lane & 3) ^ (sr & 3);          // swizzled kchunk 0..3
  const unsigned short* gA =
      A + (size_t)(m_blk + wave * 32 + sr) * Hdim + sq * 8;
  const unsigned short* gB =
      Bw + (size_t)(n_blk + wave * 32 + sr) * Hdim + sq * 8;
  unsigned short* lA0 = lA + wave * 1024;        // wave's two 16-row blocks
  unsigned short* lB0 = lB + wave * 1024;

  // fragment-read pointers
  const int wm = (wave >> 1) * 64;
  const int wn = (wave & 1) * 64;
  const int lrow = lane & 15;
  const int lkc = lane >> 4;
  const int ca = (lrow * 4 + (lkc ^ (lrow & 3))) * 8;  // swizzled chunk, in shorts
  const unsigned short* pa = lA + (wm >> 4) * 512 + ca;  // + mi*512
  const unsigned short* pb = lB + (wn >> 4) * 512 + ca;

  floatx4 acc[4][4] = {};

  for (int kt = 0; kt < Hdim / BK; ++kt) {
    __syncthreads();  // previous iter done reading LDS
#define GLL(src, dst)                                                  \
    __builtin_amdgcn_global_load_lds(                                  \
        (const __attribute__((address_space(1))) void*)(src),          \
        (__attribute__((address_space(3))) void*)(dst), 16, 0, 0)
    GLL(gA, lA0);                            // A rows wave*32 .. +16
    GLL(gA + 16 * Hdim, lA0 + 512);          // A rows +16 .. +32
    GLL(gB, lB0);
    GLL(gB + 16 * Hdim, lB0 + 512);
#undef GLL
    gA += BK;
    gB += BK;
    __syncthreads();  // staging visible

    bf16x8 af[4], bfr[4];
#pragma unroll
    for (int i = 0; i < 4; ++i) {
      af[i]  = *reinterpret_cast<const bf16x8*>(pa + i * 512);
      bfr[i] = *reinterpret_cast<const bf16x8*>(pb + i * 512);
    }
#pragma unroll
    for (int mi = 0; mi < 4; ++mi)
#pragma unroll
      for (int ni = 0; ni < 4; ++ni)
        acc[mi][ni] = __builtin_amdgcn_mfma_f32_16x16x32_bf16(
            af[mi], bfr[ni], acc[mi][ni], 0, 0, 0);
  }

  // epilogue: C/D layout col=lane&15, row=(lane>>4)*4+reg  [m89-verified]
  const int col0 = n_blk + wn + lrow;
  const int row0 = m_blk + wm + lkc * 4;
#pragma unroll
  for (int ni = 0; ni < 4; ++ni) {
    const float bs = bias[col0 + ni * 16];
#pragma unroll
    for (int mi = 0; mi < 4; ++mi) {
      float* cp = C + (size_t)(row0 + mi * 16) * Ldim + (col0 + ni * 16);
      floatx4 v = acc[mi][ni];
      cp[0 * (size_t)Ldim] = v.x + bs;
      cp[1 * (size_t)Ldim] = v.y + bs;
      cp[2 * (size_t)Ldim] = v.z + bs;
      cp[3 * (size_t)Ldim] = v.w + bs;
    }
  }
}

extern "C" void kernel_launch(void* const* d_in, const int* in_sizes, int n_in,
                              void* d_out, int out_size, void* d_ws, size_t ws_size,
                              hipStream_t stream) {
  const float* X = (const float*)d_in[0];  // bert_output [B,H]
  const float* E = (const float*)d_in[1];  // label_embed [L,H]
  const float* W = (const float*)d_in[2];  // W [L,H]
  const float* b = (const float*)d_in[3];  // b [L]
  // d_in[4] = labels, unused by the reference output.
  float* out = (float*)d_out;

  unsigned short* Xb = (unsigned short*)d_ws;                 // 8 MB
  unsigned short* Wb = Xb + (size_t)Bdim * Hdim;              // 8 MB
  float* bias = (float*)(Wb + (size_t)Ldim * Hdim);           // 16 KB

  prep_kernel<<<Ldim + Bdim, 256, 0, stream>>>(X, E, W, b, Xb, Wb, bias);
  dim3 grid(Ldim / TILE, Bdim / TILE);
  gemm_bias_kernel<<<grid, 256, 0, stream>>>(Xb, Wb, bias, out);
}